// Round 1
// 948.199 us; speedup vs baseline: 1.1647x; 1.1647x over previous
//
#include <hip/hip_runtime.h>

typedef _Float16 f16;
typedef _Float16 f16x2 __attribute__((ext_vector_type(2)));
typedef _Float16 f16x4 __attribute__((ext_vector_type(4)));
typedef _Float16 f16x8 __attribute__((ext_vector_type(8)));
typedef float f32x4 __attribute__((ext_vector_type(4)));

__device__ __forceinline__ float sigf(float x){ return 1.f/(1.f + __expf(-x)); }
__device__ __forceinline__ float tanhfast(float x){ return 2.f/(1.f + __expf(-2.f*x)) - 1.f; }
__device__ __forceinline__ float fdot2f(f16x2 a, f16x2 b, float c){
#if __has_builtin(__builtin_amdgcn_fdot2)
  return __builtin_amdgcn_fdot2(a, b, c, false);
#else
  return c + (float)a.x*(float)b.x + (float)a.y*(float)b.y;
#endif
}

// ---------------- weight prep kernels (Bpack layout: [k>>3][n][k&7]) ----------------
__global__ void prep_w1(const float* __restrict__ w, f16* __restrict__ dst){
  int idx = blockIdx.x*256 + threadIdx.x;            // 32*4*8*8 = 8192
  if (idx >= 8192) return;
  int och = idx >> 8, rem = idx & 255;
  int c = rem >> 6, ky = (rem >> 3) & 7, kx = rem & 7;
  int k = c*64 + ky*8 + kx;                           // K-order (c,ky,kx), K=256
  dst[(k>>3)*256 + och*8 + (k&7)] = (f16)(w[idx] * (1.f/255.f));  // fold x/255
}
__global__ void prep_w2(const float* __restrict__ w, f16* __restrict__ dst){
  int idx = blockIdx.x*256 + threadIdx.x;            // 64*32*4*4 = 32768
  if (idx >= 32768) return;
  int och = idx >> 9;
  int c = (idx >> 4) & 31, ky = (idx >> 2) & 3, kx = idx & 3;
  int k = (ky*4 + kx)*32 + c;                         // K=512
  dst[(k>>3)*512 + och*8 + (k&7)] = (f16)w[idx];
}
__global__ void prep_w3(const float* __restrict__ w, f16* __restrict__ dst){
  int idx = blockIdx.x*256 + threadIdx.x;            // 64*64*3*3 = 36864
  if (idx >= 36864) return;
  int och = idx / 576, r = idx % 576;
  int c = r / 9, r2 = r % 9;
  int ky = r2 / 3, kx = r2 % 3;
  int k = (ky*3 + kx)*64 + c;                         // K=576
  dst[(k>>3)*512 + och*8 + (k&7)] = (f16)w[idx];
}
__global__ void prep_wf(const float* __restrict__ w, f16* __restrict__ dst){
  int idx = blockIdx.x*256 + threadIdx.x;            // 392*512*8 = 1605632
  if (idx >= 392*512*8) return;
  int j = idx & 7, n = (idx >> 3) & 511, k8 = idx >> 12;
  int kf = k8*8 + j;
  int c = kf & 63, p = kf >> 6;                      // p = iy*7+ix (0..48)
  dst[idx] = (f16)w[(size_t)n*3136 + c*49 + p];
}
__global__ void prep_wih(const float* __restrict__ w, f16* __restrict__ dst){
  int idx = blockIdx.x*256 + threadIdx.x;            // 64*512*8 = 262144
  if (idx >= 262144) return;
  int j = idx & 7, n = (idx >> 3) & 511, k8 = idx >> 12;
  dst[idx] = (f16)w[n*512 + k8*8 + j];               // fully coalesced r+w
}
__global__ void prep_wheads(const float* __restrict__ wa, const float* __restrict__ wc,
                            f16* __restrict__ dst){
  int idx = blockIdx.x*256 + threadIdx.x;            // 32*128 (pad N 19->32)
  if (idx >= 4096) return;
  int n = idx >> 7, k = idx & 127;
  float v = 0.f;
  if (n < 18) v = wa[n*128 + k];
  else if (n == 18) v = wc[k];
  dst[(k>>3)*256 + n*8 + (k&7)] = (f16)v;
}
__global__ void prep_bsum(const float* __restrict__ a, const float* __restrict__ b,
                          float* __restrict__ s){
  int i = blockIdx.x*256 + threadIdx.x;
  if (i < 512) s[i] = a[i] + b[i];
}
// whhT2 layout: [k2=k/2][n=0..511][k&1] fp16 -> coalesced f16x2 loads per (k2, gate)
__global__ void prep_whh(const float* __restrict__ w, f16* __restrict__ dst){
  int idx = blockIdx.x*256 + threadIdx.x;            // 512*128 = 65536
  if (idx >= 65536) return;
  int nn = idx >> 7, k = idx & 127;
  dst[(k >> 1)*1024 + nn*2 + (k & 1)] = (f16)w[idx];
}

// ---------------- fused conv trunk: x frame -> y3 (49*64 fp16), all LDS-resident ----------------
// one block per frame: conv1 in two 10-row halves (x half staged fp16), y1 frame in LDS,
// conv2 -> y2 aliased onto the dead x buffer, conv3 -> global y3.
__global__ __launch_bounds__(256) void conv123_k(const float* __restrict__ x,
    const f16* __restrict__ Bp1, const float* __restrict__ b1,
    const f16* __restrict__ Bp2, const float* __restrict__ b2,
    const f16* __restrict__ Bp3, const float* __restrict__ b3,
    f16* __restrict__ y3){
  __shared__ alignas(16) f16 xt[4*44*84];            // 29568 B; reused as y2 (81*64=10368 B)
  __shared__ alignas(16) f16 y1t[400*32];            // 25600 B   (total 55168 B -> 2 blk/CU)
  int n = blockIdx.x;
  int tid = threadIdx.x;
  int lane = tid & 63, w = tid >> 6;
  int q = lane >> 4, m = lane & 15;

  // ---- conv1: 2 waves-groups x 16 och, 2 m-groups, two y-halves ----
  int wg = w & 1, wm = w >> 1;
  int och1 = wg*16 + m;
  f16x8 bfr1[8];
  #pragma unroll
  for (int s = 0; s < 8; ++s)
    bfr1[s] = *(const f16x8*)(Bp1 + ((4*s + q)*32 + och1)*8);
  float bias1 = b1[och1];

  #pragma unroll
  for (int h = 0; h < 2; ++h){
    // stage input rows h*40 .. h*40+43 (4 ch), fp32 -> fp16 planar [c][44][84]
    for (int i = tid; i < 3696; i += 256){
      int c = i / 924, r = i % 924;
      int iy = r / 21, x4 = r % 21;
      const float4* xp = (const float4*)(x + (((size_t)n*4 + c)*84 + h*40 + iy)*84) + x4;
      float4 v = *xp;
      f16x4 hv = { (f16)v.x, (f16)v.y, (f16)v.z, (f16)v.w };
      *(f16x4*)(&xt[(c*44 + iy)*84 + x4*4]) = hv;
    }
    __syncthreads();
    int oy4[7], ox4[7];
    #pragma unroll
    for (int i = 0; i < 7; ++i){
      int pxl = (wm*7 + i)*16 + m; if (pxl > 199) pxl = 199;
      oy4[i] = (pxl/20)*4; ox4[i] = (pxl%20)*4;
    }
    f32x4 acc1[7] = {};
    #pragma unroll
    for (int s = 0; s < 8; ++s){
      int k8 = 4*s + q;
      int c = k8 >> 3, ky = k8 & 7;                  // K-order (c,ky,kx)
      #pragma unroll
      for (int i = 0; i < 7; ++i){
        const f16* ap = &xt[(c*44 + oy4[i] + ky)*84 + ox4[i]];
        f16x4 lo = *(const f16x4*)ap;
        f16x4 hi = *(const f16x4*)(ap + 4);
        f16x8 a = __builtin_shufflevector(lo, hi, 0,1,2,3,4,5,6,7);
        acc1[i] = __builtin_amdgcn_mfma_f32_16x16x32_f16(a, bfr1[s], acc1[i], 0, 0, 0);
      }
    }
    #pragma unroll
    for (int i = 0; i < 7; ++i)
      #pragma unroll
      for (int r = 0; r < 4; ++r){
        int pxl = (wm*7 + i)*16 + q*4 + r;
        if (pxl < 200){
          float v = acc1[i][r] + bias1; v = v > 0.f ? v : 0.f;
          y1t[(h*200 + pxl)*32 + och1] = (f16)v;
        }
      }
    __syncthreads();                                  // y1 half done; xt free for restage
  }

  // ---- conv2: y1t (20x20x32) -> y2 (9x9x64) in xt, each wave 16 och x 81 px ----
  int och2 = w*16 + m;
  f16x8 bfr2[16];
  #pragma unroll
  for (int s = 0; s < 16; ++s)
    bfr2[s] = *(const f16x8*)(Bp2 + ((size_t)(4*s + q)*64 + och2)*8);
  int basev[6];
  #pragma unroll
  for (int i = 0; i < 6; ++i){
    int px = i*16 + m; if (px > 80) px = 80;
    basev[i] = (px/9*2)*20 + (px%9)*2;
  }
  f32x4 acc2[6] = {};
  #pragma unroll
  for (int s = 0; s < 16; ++s){
    int k8 = 4*s + q;
    int c0 = (k8 & 3)*8;
    int kk = k8 >> 2;
    int off = ((kk >> 2)*20 + (kk & 3))*32 + c0;     // (ky*20+kx)*32+c0
    #pragma unroll
    for (int i = 0; i < 6; ++i){
      f16x8 a = *(const f16x8*)(&y1t[basev[i]*32 + off]);
      acc2[i] = __builtin_amdgcn_mfma_f32_16x16x32_f16(a, bfr2[s], acc2[i], 0, 0, 0);
    }
  }
  float bias2 = b2[och2];
  #pragma unroll
  for (int i = 0; i < 6; ++i)
    #pragma unroll
    for (int r = 0; r < 4; ++r){
      int px = i*16 + q*4 + r;
      if (px < 81){
        float v = acc2[i][r] + bias2; v = v > 0.f ? v : 0.f;
        xt[px*64 + och2] = (f16)v;                    // y2 lives in xt (xt dead)
      }
    }
  __syncthreads();

  // ---- conv3: y2 (9x9x64) -> y3 global (49x64), each wave 16 och x 49 px ----
  int basev3[4];
  #pragma unroll
  for (int i = 0; i < 4; ++i){
    int px = i*16 + m; if (px > 48) px = 48;
    basev3[i] = (px/7)*9 + (px%7);
  }
  f32x4 acc3[4] = {};
  for (int s = 0; s < 18; ++s){
    int k8 = 4*s + q;
    int c0 = (k8 & 7)*8;
    int kxy = k8 >> 3;
    int ky = kxy/3, kx = kxy%3;
    f16x8 b = *(const f16x8*)(Bp3 + ((size_t)k8*64 + och2)*8);
    int off = (ky*9 + kx)*64 + c0;
    #pragma unroll
    for (int i = 0; i < 4; ++i){
      f16x8 a = *(const f16x8*)(&xt[basev3[i]*64 + off]);
      acc3[i] = __builtin_amdgcn_mfma_f32_16x16x32_f16(a, b, acc3[i], 0, 0, 0);
    }
  }
  float bias3 = b3[och2];
  #pragma unroll
  for (int i = 0; i < 4; ++i)
    #pragma unroll
    for (int r = 0; r < 4; ++r){
      int px = i*16 + q*4 + r;
      if (px < 49){
        float v = acc3[i][r] + bias3; v = v > 0.f ? v : 0.f;
        y3[((size_t)n*49 + px)*64 + och2] = (f16)v;
      }
    }
}

// ---------------- generic GEMM: out(M,N) = A(M,K)fp16 @ Bpack + bias ----------------
template<bool RELU, bool OUTH>
__global__ __launch_bounds__(256) void gemm_k(const f16* __restrict__ A,
    const f16* __restrict__ Bp, const float* __restrict__ bias, void* __restrict__ out,
    int M, int N, int K){
  __shared__ alignas(16) f16 at[64*264];             // 64 rows, K_BLK=256 (+8 pad)
  int m0 = blockIdx.x*64, n0 = blockIdx.y*64;
  int lane = threadIdx.x & 63, w = threadIdx.x >> 6;
  int q = lane >> 4, cl = lane & 15;
  int mh = w >> 1, nh = w & 1;
  f32x4 acc[2][2] = {};
  for (int kb = 0; kb < K; kb += 256){
    int kblen = K - kb; if (kblen > 256) kblen = 256;
    int c8n = kblen >> 3;
    __syncthreads();
    int tot = 64*c8n;
    for (int i = threadIdx.x; i < tot; i += 256){
      int row, c8;
      if (c8n == 32){ row = i >> 5; c8 = i & 31; } else { row = i >> 3; c8 = i & 7; }
      *(f16x8*)(&at[row*264 + c8*8]) = *(const f16x8*)(&A[(size_t)(m0+row)*K + kb + c8*8]);
    }
    __syncthreads();
    int nks = kblen >> 5;
    for (int s = 0; s < nks; ++s){
      f16x8 a[2], b[2];
      #pragma unroll
      for (int mi = 0; mi < 2; ++mi)
        a[mi] = *(const f16x8*)(&at[((mh*2+mi)*16 + cl)*264 + 32*s + 8*q]);
      #pragma unroll
      for (int ni = 0; ni < 2; ++ni){
        int nn = n0 + (nh*2+ni)*16 + cl;
        b[ni] = *(const f16x8*)(&Bp[((size_t)((kb>>3) + 4*s + q)*N + nn)*8]);
      }
      #pragma unroll
      for (int mi = 0; mi < 2; ++mi)
        #pragma unroll
        for (int ni = 0; ni < 2; ++ni)
          acc[mi][ni] = __builtin_amdgcn_mfma_f32_16x16x32_f16(a[mi], b[ni], acc[mi][ni], 0,0,0);
    }
  }
  #pragma unroll
  for (int ni = 0; ni < 2; ++ni){
    int nn = n0 + (nh*2+ni)*16 + cl;
    float bv = bias[nn];
    #pragma unroll
    for (int mi = 0; mi < 2; ++mi)
      #pragma unroll
      for (int r = 0; r < 4; ++r){
        int mg = m0 + (mh*2+mi)*16 + q*4 + r;
        float v = acc[mi][ni][r] + bv;
        if (RELU) v = v > 0.f ? v : 0.f;
        if (OUTH) ((f16*)out)[(size_t)mg*N + nn] = (f16)v;
        else      ((float*)out)[(size_t)mg*N + nn] = v;
      }
  }
}

// ---------------- segmented LSTM: done==1 resets state -> independent segments ----------------
// block (t0, e) is active iff t0==0 or done[t0,e]==1; it owns steps t0..(next reset)-1.
// thread j owns hidden unit j: 4 gate dots of length 128 via v_dot2_f32_f16, coalesced
// loads from pre-transposed fp16 whhT2 [k/2][512][2]; h broadcast via 2-buffer LDS.
__global__ __launch_bounds__(128) void lstm_seg(const float* __restrict__ gx,
    const f16* __restrict__ whhT2, const int* __restrict__ done,
    const float* __restrict__ h0, const float* __restrict__ c0,
    f16* __restrict__ hs){
  int e = blockIdx.y, t0 = blockIdx.x;
  if (t0 > 0 && done[t0*32 + e] == 0) return;        // uniform early exit
  int j = threadIdx.x;
  __shared__ f16 hl[2][128];
  float h, c;
  if (t0 == 0){
    float mm = 1.f - (float)done[e];                 // done[t=0, e]
    h = h0[e*128 + j]*mm;
    c = c0[e*128 + j]*mm;
  } else { h = 0.f; c = 0.f; }                       // reset state at segment start
  int buf = 0;
  hl[0][j] = (f16)h;
  __syncthreads();
  const f16x2* wp = (const f16x2*)whhT2;
  for (int t = t0; t < 128; ++t){
    if (t > t0 && done[t*32 + e] != 0) break;        // uniform across block
    const float* gxr = gx + ((size_t)t*32 + e)*512;
    float gi = gxr[j], gf = gxr[128 + j], gg = gxr[256 + j], go = gxr[384 + j];
    const f16x2* hp = (const f16x2*)hl[buf];
    float ai = 0.f, af = 0.f, ag = 0.f, ao = 0.f;
    #pragma unroll 8
    for (int k2 = 0; k2 < 64; ++k2){
      f16x2 hv = hp[k2];                             // LDS broadcast, conflict-free
      const f16x2* wr = wp + k2*512;
      ai = fdot2f(wr[j], hv, ai);
      af = fdot2f(wr[128 + j], hv, af);
      ag = fdot2f(wr[256 + j], hv, ag);
      ao = fdot2f(wr[384 + j], hv, ao);
    }
    gi += ai; gf += af; gg += ag; go += ao;
    c = sigf(gf)*c + sigf(gi)*tanhfast(gg);
    h = sigf(go)*tanhfast(c);
    hs[((size_t)t*32 + e)*128 + j] = (f16)h;
    buf ^= 1;
    hl[buf][j] = (f16)h;                             // double buffer: 1 barrier/step
    __syncthreads();
  }
}

// ---------------- heads: (TB,128) @ [wa;wc]^T + bias -> out (TB,19) fp32 ----------------
__global__ __launch_bounds__(256) void heads_k(const f16* __restrict__ hs,
    const f16* __restrict__ Bp, const float* __restrict__ ba, const float* __restrict__ bc,
    float* __restrict__ out){
  __shared__ alignas(16) f16 at[64*128];
  int m0 = blockIdx.x*64;
  for (int i = threadIdx.x; i < 1024; i += 256)
    ((uint4*)at)[i] = ((const uint4*)(hs + (size_t)m0*128))[i];
  int lane = threadIdx.x & 63, w = threadIdx.x >> 6;
  int q = lane >> 4, cl = lane & 15;
  __syncthreads();
  f32x4 acc[2] = {};
  #pragma unroll
  for (int s = 0; s < 4; ++s){
    f16x8 a = *(const f16x8*)(&at[(w*16 + cl)*128 + 32*s + 8*q]);
    #pragma unroll
    for (int nt = 0; nt < 2; ++nt){
      f16x8 b = *(const f16x8*)(&Bp[((4*s + q)*32 + nt*16 + cl)*8]);
      acc[nt] = __builtin_amdgcn_mfma_f32_16x16x32_f16(a, b, acc[nt], 0,0,0);
    }
  }
  #pragma unroll
  for (int nt = 0; nt < 2; ++nt){
    int n = nt*16 + cl;
    if (n < 19){
      float bv = (n < 18) ? ba[n] : bc[0];
      #pragma unroll
      for (int r = 0; r < 4; ++r){
        int m = m0 + w*16 + q*4 + r;
        out[(size_t)m*19 + n] = acc[nt][r] + bv;
      }
    }
  }
}

extern "C" void kernel_launch(void* const* d_in, const int* in_sizes, int n_in,
                              void* d_out, int out_size, void* d_ws, size_t ws_size,
                              hipStream_t stream){
  const float* x   = (const float*)d_in[0];
  const int*   dn  = (const int*)d_in[1];
  const float* h0  = (const float*)d_in[2];
  const float* c0  = (const float*)d_in[3];
  const float* w1  = (const float*)d_in[4];
  const float* b1  = (const float*)d_in[5];
  const float* w2  = (const float*)d_in[6];
  const float* b2  = (const float*)d_in[7];
  const float* w3  = (const float*)d_in[8];
  const float* b3  = (const float*)d_in[9];
  const float* wf  = (const float*)d_in[10];
  const float* bf  = (const float*)d_in[11];
  const float* wih = (const float*)d_in[12];
  const float* whh = (const float*)d_in[13];
  const float* bih = (const float*)d_in[14];
  const float* bhh = (const float*)d_in[15];
  const float* wa  = (const float*)d_in[16];
  const float* ba  = (const float*)d_in[17];
  const float* wc  = (const float*)d_in[18];
  const float* bc  = (const float*)d_in[19];
  float* out = (float*)d_out;

  char* ws = (char*)d_ws;
  size_t off = 0;
  auto alloc = [&](size_t bytes)->char*{
    char* p = ws + off;
    off += (bytes + 255) & ~(size_t)255;
    return p;
  };
  f16*  y3   = (f16*)alloc(4096UL*3136*2);     // 25.7 MB (only trunk intermediate in HBM)
  f16*  feat = (f16*)alloc(4096UL*512*2);
  float* gx  = (float*)alloc(4096UL*512*4);
  f16*  hs   = (f16*)alloc(4096UL*128*2);
  f16*  Bp1  = (f16*)alloc(32UL*32*8*2);
  f16*  Bp2  = (f16*)alloc(64UL*64*8*2);
  f16*  Bp3  = (f16*)alloc(72UL*64*8*2);
  f16*  Bpf  = (f16*)alloc(392UL*512*8*2);
  f16*  Bpih = (f16*)alloc(64UL*512*8*2);
  f16*  Bph  = (f16*)alloc(16UL*32*8*2);
  float* bsum = (float*)alloc(512UL*4);
  f16*  whhT2 = (f16*)alloc(64UL*512*2*2);     // 128 KB, L2-resident per XCD

  prep_w1<<<32, 256, 0, stream>>>(w1, Bp1);
  prep_w2<<<128, 256, 0, stream>>>(w2, Bp2);
  prep_w3<<<144, 256, 0, stream>>>(w3, Bp3);
  prep_wf<<<6272, 256, 0, stream>>>(wf, Bpf);
  prep_wih<<<1024, 256, 0, stream>>>(wih, Bpih);
  prep_wheads<<<16, 256, 0, stream>>>(wa, wc, Bph);
  prep_bsum<<<2, 256, 0, stream>>>(bih, bhh, bsum);
  prep_whh<<<256, 256, 0, stream>>>(whh, whhT2);

  conv123_k<<<4096, 256, 0, stream>>>(x, Bp1, b1, Bp2, b2, Bp3, b3, y3);
  gemm_k<true,  true ><<<dim3(64, 8), 256, 0, stream>>>(y3,   Bpf,  bf,   (void*)feat, 4096, 512, 3136);
  gemm_k<false, false><<<dim3(64, 8), 256, 0, stream>>>(feat, Bpih, bsum, (void*)gx,   4096, 512, 512);
  lstm_seg<<<dim3(128, 32), 128, 0, stream>>>(gx, whhT2, dn, h0, c0, hs);
  heads_k<<<64, 256, 0, stream>>>(hs, Bph, ba, bc, out);
}

// Round 2
// 897.596 us; speedup vs baseline: 1.2304x; 1.0564x over previous
//
#include <hip/hip_runtime.h>

typedef _Float16 f16;
typedef _Float16 f16x2 __attribute__((ext_vector_type(2)));
typedef _Float16 f16x4 __attribute__((ext_vector_type(4)));
typedef _Float16 f16x8 __attribute__((ext_vector_type(8)));
typedef float f32x4 __attribute__((ext_vector_type(4)));

__device__ __forceinline__ float sigf(float x){ return 1.f/(1.f + __expf(-x)); }
__device__ __forceinline__ float tanhfast(float x){ return 2.f/(1.f + __expf(-2.f*x)) - 1.f; }
__device__ __forceinline__ float fdot2f(f16x2 a, f16x2 b, float c){
#if __has_builtin(__builtin_amdgcn_fdot2)
  return __builtin_amdgcn_fdot2(a, b, c, false);
#else
  return c + (float)a.x*(float)b.x + (float)a.y*(float)b.y;
#endif
}

// ---------------- weight prep kernels (Bpack layout: [k>>3][n][k&7]) ----------------
__global__ void prep_w1(const float* __restrict__ w, f16* __restrict__ dst){
  int idx = blockIdx.x*256 + threadIdx.x;            // 32*4*8*8 = 8192
  if (idx >= 8192) return;
  int och = idx >> 8, rem = idx & 255;
  int c = rem >> 6, ky = (rem >> 3) & 7, kx = rem & 7;
  int k = c*64 + ky*8 + kx;                           // K-order (c,ky,kx), K=256
  dst[(k>>3)*256 + och*8 + (k&7)] = (f16)(w[idx] * (1.f/255.f));  // fold x/255
}
__global__ void prep_w2(const float* __restrict__ w, f16* __restrict__ dst){
  int idx = blockIdx.x*256 + threadIdx.x;            // 64*32*4*4 = 32768
  if (idx >= 32768) return;
  int och = idx >> 9;
  int c = (idx >> 4) & 31, ky = (idx >> 2) & 3, kx = idx & 3;
  int k = (ky*4 + kx)*32 + c;                         // K=512
  dst[(k>>3)*512 + och*8 + (k&7)] = (f16)w[idx];
}
__global__ void prep_w3(const float* __restrict__ w, f16* __restrict__ dst){
  int idx = blockIdx.x*256 + threadIdx.x;            // 64*64*3*3 = 36864
  if (idx >= 36864) return;
  int och = idx / 576, r = idx % 576;
  int c = r / 9, r2 = r % 9;
  int ky = r2 / 3, kx = r2 % 3;
  int k = (ky*3 + kx)*64 + c;                         // K=576
  dst[(k>>3)*512 + och*8 + (k&7)] = (f16)w[idx];
}
__global__ void prep_wf(const float* __restrict__ w, f16* __restrict__ dst){
  int idx = blockIdx.x*256 + threadIdx.x;            // 392*512*8 = 1605632
  if (idx >= 392*512*8) return;
  int j = idx & 7, n = (idx >> 3) & 511, k8 = idx >> 12;
  int kf = k8*8 + j;
  int c = kf & 63, p = kf >> 6;                      // p = iy*7+ix (0..48)
  dst[idx] = (f16)w[(size_t)n*3136 + c*49 + p];
}
__global__ void prep_wih(const float* __restrict__ w, f16* __restrict__ dst){
  int idx = blockIdx.x*256 + threadIdx.x;            // 64*512*8 = 262144
  if (idx >= 262144) return;
  int j = idx & 7, n = (idx >> 3) & 511, k8 = idx >> 12;
  dst[idx] = (f16)w[n*512 + k8*8 + j];               // fully coalesced r+w
}
__global__ void prep_wheads(const float* __restrict__ wa, const float* __restrict__ wc,
                            f16* __restrict__ dst){
  int idx = blockIdx.x*256 + threadIdx.x;            // 32*128 (pad N 19->32)
  if (idx >= 4096) return;
  int n = idx >> 7, k = idx & 127;
  float v = 0.f;
  if (n < 18) v = wa[n*128 + k];
  else if (n == 18) v = wc[k];
  dst[(k>>3)*256 + n*8 + (k&7)] = (f16)v;
}
__global__ void prep_bsum(const float* __restrict__ a, const float* __restrict__ b,
                          float* __restrict__ s){
  int i = blockIdx.x*256 + threadIdx.x;
  if (i < 512) s[i] = a[i] + b[i];
}
// whhT2 layout: [k2=k/2][n=0..511][k&1] fp16 -> coalesced f16x2 loads per (k2, gate)
__global__ void prep_whh(const float* __restrict__ w, f16* __restrict__ dst){
  int idx = blockIdx.x*256 + threadIdx.x;            // 512*128 = 65536
  if (idx >= 65536) return;
  int nn = idx >> 7, k = idx & 127;
  dst[(k >> 1)*1024 + nn*2 + (k & 1)] = (f16)w[idx];
}

// ---------------- fused conv trunk: x frame -> y3 (49*64 fp16), all LDS-resident ----------------
// one block per frame. conv1 in FOUR 24-input-row slabs (xt = 16.1 KB) -> y1t frame (25.6 KB,
// XOR-swizzled), conv2 -> y2 in xt (XOR-swizzled), conv3 -> global y3.
// LDS total 41.7 KB -> 3 blocks/CU. Swizzles: y1t idx^=((p>>1)&7)<<3 ; y2 idx^=(p&7)<<3
// (both sides of each tensor) -> every ds_read_b128 pattern is <=2-way (free).
__global__ __launch_bounds__(256, 3) void conv123_k(const float* __restrict__ x,
    const f16* __restrict__ Bp1, const float* __restrict__ b1,
    const f16* __restrict__ Bp2, const float* __restrict__ b2,
    const f16* __restrict__ Bp3, const float* __restrict__ b3,
    f16* __restrict__ y3){
  __shared__ alignas(16) f16 xt[4*24*84];            // 16128 B; reused as y2 (81*64 swz, 10.4 KB)
  __shared__ alignas(16) f16 y1t[400*32];            // 25600 B  (total 41728 B -> 3 blk/CU)
  int n = blockIdx.x;
  int tid = threadIdx.x;
  int lane = tid & 63, w = tid >> 6;
  int q = lane >> 4, m = lane & 15;

  // ---- conv1: 2 och-groups x 2 px-halves, 4 slabs of 5 output rows ----
  int wg = w & 1, wm = w >> 1;
  int och1 = wg*16 + m;
  f16x8 bfr1[8];
  #pragma unroll
  for (int s = 0; s < 8; ++s)
    bfr1[s] = *(const f16x8*)(Bp1 + ((4*s + q)*32 + och1)*8);
  float bias1 = b1[och1];

  #pragma unroll
  for (int h = 0; h < 4; ++h){
    // stage input rows h*20 .. h*20+23 (4 ch), fp32 -> fp16 planar [c][24][84]
    for (int i = tid; i < 2016; i += 256){
      int c = i / 504, r = i % 504;
      int iy = r / 21, x4 = r % 21;
      const float4* xp = (const float4*)(x + (((size_t)n*4 + c)*84 + h*20 + iy)*84) + x4;
      float4 v = *xp;
      f16x4 hv = { (f16)v.x, (f16)v.y, (f16)v.z, (f16)v.w };
      *(f16x4*)(&xt[(c*24 + iy)*84 + x4*4]) = hv;
    }
    __syncthreads();
    // local px 0..99 (5 out rows x 20); this wave: half wm (50 px), 4 m-tiles
    int oy4[4], ox4[4];
    #pragma unroll
    for (int i = 0; i < 4; ++i){
      int pl = i*16 + m; if (pl > 49) pl = 49;
      int p = wm*50 + pl;
      oy4[i] = (p/20)*4; ox4[i] = (p%20)*4;
    }
    f32x4 acc1[4] = {};
    #pragma unroll
    for (int s = 0; s < 8; ++s){
      int k8 = 4*s + q;
      int c = k8 >> 3, ky = k8 & 7;                  // K-order (c,ky,kx)
      #pragma unroll
      for (int i = 0; i < 4; ++i){
        const f16* ap = &xt[(c*24 + oy4[i] + ky)*84 + ox4[i]];
        f16x4 lo = *(const f16x4*)ap;
        f16x4 hi = *(const f16x4*)(ap + 4);
        f16x8 a = __builtin_shufflevector(lo, hi, 0,1,2,3,4,5,6,7);
        acc1[i] = __builtin_amdgcn_mfma_f32_16x16x32_f16(a, bfr1[s], acc1[i], 0, 0, 0);
      }
    }
    #pragma unroll
    for (int i = 0; i < 4; ++i)
      #pragma unroll
      for (int r = 0; r < 4; ++r){
        int pl = i*16 + q*4 + r;
        if (pl < 50){
          int P = h*100 + wm*50 + pl;                // global y1 pixel 0..399
          float v = acc1[i][r] + bias1; v = v > 0.f ? v : 0.f;
          int idx = (P*32 + och1) ^ (((P>>1)&7)<<3); // swizzled write
          y1t[idx] = (f16)v;
        }
      }
    __syncthreads();                                  // y1 slab done; xt free for restage
  }

  // ---- conv2: y1t (20x20x32 swz) -> y2 (9x9x64 swz) in xt, each wave 16 och x 81 px ----
  int och2 = w*16 + m;
  f16x8 bfr2[16];
  #pragma unroll
  for (int s = 0; s < 16; ++s)
    bfr2[s] = *(const f16x8*)(Bp2 + ((size_t)(4*s + q)*64 + och2)*8);
  int basev[6];
  #pragma unroll
  for (int i = 0; i < 6; ++i){
    int px = i*16 + m; if (px > 80) px = 80;
    basev[i] = (px/9*2)*20 + (px%9)*2;
  }
  f32x4 acc2[6] = {};
  #pragma unroll
  for (int s = 0; s < 16; ++s){
    int k8 = 4*s + q;
    int c0 = (k8 & 3)*8;
    int kk = k8 >> 2;
    int poff = (kk >> 2)*20 + (kk & 3);              // ky*20+kx
    #pragma unroll
    for (int i = 0; i < 6; ++i){
      int p = basev[i] + poff;
      int idx = (p*32 + c0) ^ (((p>>1)&7)<<3);       // swizzled read
      f16x8 a = *(const f16x8*)(&y1t[idx]);
      acc2[i] = __builtin_amdgcn_mfma_f32_16x16x32_f16(a, bfr2[s], acc2[i], 0, 0, 0);
    }
  }
  float bias2 = b2[och2];
  #pragma unroll
  for (int i = 0; i < 6; ++i)
    #pragma unroll
    for (int r = 0; r < 4; ++r){
      int px = i*16 + q*4 + r;
      if (px < 81){
        float v = acc2[i][r] + bias2; v = v > 0.f ? v : 0.f;
        int idx = (px*64 + och2) ^ ((px&7)<<3);      // y2 lives in xt, swizzled
        xt[idx] = (f16)v;
      }
    }
  __syncthreads();

  // ---- conv3: y2 (9x9x64 swz) -> y3 global (49x64), each wave 16 och x 49 px ----
  int basev3[4];
  #pragma unroll
  for (int i = 0; i < 4; ++i){
    int px = i*16 + m; if (px > 48) px = 48;
    basev3[i] = (px/7)*9 + (px%7);
  }
  f32x4 acc3[4] = {};
  for (int s = 0; s < 18; ++s){
    int k8 = 4*s + q;
    int c0 = (k8 & 7)*8;
    int kxy = k8 >> 3;
    int ky = kxy/3, kx = kxy%3;
    f16x8 b = *(const f16x8*)(Bp3 + ((size_t)k8*64 + och2)*8);
    int poff = ky*9 + kx;
    #pragma unroll
    for (int i = 0; i < 4; ++i){
      int p = basev3[i] + poff;
      int idx = (p*64 + c0) ^ ((p&7)<<3);            // swizzled read
      f16x8 a = *(const f16x8*)(&xt[idx]);
      acc3[i] = __builtin_amdgcn_mfma_f32_16x16x32_f16(a, b, acc3[i], 0, 0, 0);
    }
  }
  float bias3 = b3[och2];
  #pragma unroll
  for (int i = 0; i < 4; ++i)
    #pragma unroll
    for (int r = 0; r < 4; ++r){
      int px = i*16 + q*4 + r;
      if (px < 49){
        float v = acc3[i][r] + bias3; v = v > 0.f ? v : 0.f;
        y3[((size_t)n*49 + px)*64 + och2] = (f16)v;
      }
    }
}

// ---------------- generic GEMM: out(M,N) = A(M,K)fp16 @ Bpack + bias ----------------
template<bool RELU, bool OUTH>
__global__ __launch_bounds__(256) void gemm_k(const f16* __restrict__ A,
    const f16* __restrict__ Bp, const float* __restrict__ bias, void* __restrict__ out,
    int M, int N, int K){
  __shared__ alignas(16) f16 at[64*264];             // 64 rows, K_BLK=256 (+8 pad)
  int m0 = blockIdx.x*64, n0 = blockIdx.y*64;
  int lane = threadIdx.x & 63, w = threadIdx.x >> 6;
  int q = lane >> 4, cl = lane & 15;
  int mh = w >> 1, nh = w & 1;
  f32x4 acc[2][2] = {};
  for (int kb = 0; kb < K; kb += 256){
    int kblen = K - kb; if (kblen > 256) kblen = 256;
    int c8n = kblen >> 3;
    __syncthreads();
    int tot = 64*c8n;
    for (int i = threadIdx.x; i < tot; i += 256){
      int row, c8;
      if (c8n == 32){ row = i >> 5; c8 = i & 31; } else { row = i >> 3; c8 = i & 7; }
      *(f16x8*)(&at[row*264 + c8*8]) = *(const f16x8*)(&A[(size_t)(m0+row)*K + kb + c8*8]);
    }
    __syncthreads();
    int nks = kblen >> 5;
    for (int s = 0; s < nks; ++s){
      f16x8 a[2], b[2];
      #pragma unroll
      for (int mi = 0; mi < 2; ++mi)
        a[mi] = *(const f16x8*)(&at[((mh*2+mi)*16 + cl)*264 + 32*s + 8*q]);
      #pragma unroll
      for (int ni = 0; ni < 2; ++ni){
        int nn = n0 + (nh*2+ni)*16 + cl;
        b[ni] = *(const f16x8*)(&Bp[((size_t)((kb>>3) + 4*s + q)*N + nn)*8]);
      }
      #pragma unroll
      for (int mi = 0; mi < 2; ++mi)
        #pragma unroll
        for (int ni = 0; ni < 2; ++ni)
          acc[mi][ni] = __builtin_amdgcn_mfma_f32_16x16x32_f16(a[mi], b[ni], acc[mi][ni], 0,0,0);
    }
  }
  #pragma unroll
  for (int ni = 0; ni < 2; ++ni){
    int nn = n0 + (nh*2+ni)*16 + cl;
    float bv = bias[nn];
    #pragma unroll
    for (int mi = 0; mi < 2; ++mi)
      #pragma unroll
      for (int r = 0; r < 4; ++r){
        int mg = m0 + (mh*2+mi)*16 + q*4 + r;
        float v = acc[mi][ni][r] + bv;
        if (RELU) v = v > 0.f ? v : 0.f;
        if (OUTH) ((f16*)out)[(size_t)mg*N + nn] = (f16)v;
        else      ((float*)out)[(size_t)mg*N + nn] = v;
      }
  }
}

// ---------------- segmented LSTM: done==1 resets state -> independent segments ----------------
__global__ __launch_bounds__(128) void lstm_seg(const float* __restrict__ gx,
    const f16* __restrict__ whhT2, const int* __restrict__ done,
    const float* __restrict__ h0, const float* __restrict__ c0,
    f16* __restrict__ hs){
  int e = blockIdx.y, t0 = blockIdx.x;
  if (t0 > 0 && done[t0*32 + e] == 0) return;        // uniform early exit
  int j = threadIdx.x;
  __shared__ f16 hl[2][128];
  float h, c;
  if (t0 == 0){
    float mm = 1.f - (float)done[e];                 // done[t=0, e]
    h = h0[e*128 + j]*mm;
    c = c0[e*128 + j]*mm;
  } else { h = 0.f; c = 0.f; }                       // reset state at segment start
  int buf = 0;
  hl[0][j] = (f16)h;
  __syncthreads();
  const f16x2* wp = (const f16x2*)whhT2;
  for (int t = t0; t < 128; ++t){
    if (t > t0 && done[t*32 + e] != 0) break;        // uniform across block
    const float* gxr = gx + ((size_t)t*32 + e)*512;
    float gi = gxr[j], gf = gxr[128 + j], gg = gxr[256 + j], go = gxr[384 + j];
    const f16x2* hp = (const f16x2*)hl[buf];
    float ai = 0.f, af = 0.f, ag = 0.f, ao = 0.f;
    #pragma unroll 8
    for (int k2 = 0; k2 < 64; ++k2){
      f16x2 hv = hp[k2];                             // LDS broadcast, conflict-free
      const f16x2* wr = wp + k2*512;
      ai = fdot2f(wr[j], hv, ai);
      af = fdot2f(wr[128 + j], hv, af);
      ag = fdot2f(wr[256 + j], hv, ag);
      ao = fdot2f(wr[384 + j], hv, ao);
    }
    gi += ai; gf += af; gg += ag; go += ao;
    c = sigf(gf)*c + sigf(gi)*tanhfast(gg);
    h = sigf(go)*tanhfast(c);
    hs[((size_t)t*32 + e)*128 + j] = (f16)h;
    buf ^= 1;
    hl[buf][j] = (f16)h;                             // double buffer: 1 barrier/step
    __syncthreads();
  }
}

// ---------------- heads: (TB,128) @ [wa;wc]^T + bias -> out (TB,19) fp32 ----------------
__global__ __launch_bounds__(256) void heads_k(const f16* __restrict__ hs,
    const f16* __restrict__ Bp, const float* __restrict__ ba, const float* __restrict__ bc,
    float* __restrict__ out){
  __shared__ alignas(16) f16 at[64*128];
  int m0 = blockIdx.x*64;
  for (int i = threadIdx.x; i < 1024; i += 256)
    ((uint4*)at)[i] = ((const uint4*)(hs + (size_t)m0*128))[i];
  int lane = threadIdx.x & 63, w = threadIdx.x >> 6;
  int q = lane >> 4, cl = lane & 15;
  __syncthreads();
  f32x4 acc[2] = {};
  #pragma unroll
  for (int s = 0; s < 4; ++s){
    f16x8 a = *(const f16x8*)(&at[(w*16 + cl)*128 + 32*s + 8*q]);
    #pragma unroll
    for (int nt = 0; nt < 2; ++nt){
      f16x8 b = *(const f16x8*)(&Bp[((4*s + q)*32 + nt*16 + cl)*8]);
      acc[nt] = __builtin_amdgcn_mfma_f32_16x16x32_f16(a, b, acc[nt], 0,0,0);
    }
  }
  #pragma unroll
  for (int nt = 0; nt < 2; ++nt){
    int n = nt*16 + cl;
    if (n < 19){
      float bv = (n < 18) ? ba[n] : bc[0];
      #pragma unroll
      for (int r = 0; r < 4; ++r){
        int m = m0 + w*16 + q*4 + r;
        out[(size_t)m*19 + n] = acc[nt][r] + bv;
      }
    }
  }
}

extern "C" void kernel_launch(void* const* d_in, const int* in_sizes, int n_in,
                              void* d_out, int out_size, void* d_ws, size_t ws_size,
                              hipStream_t stream){
  const float* x   = (const float*)d_in[0];
  const int*   dn  = (const int*)d_in[1];
  const float* h0  = (const float*)d_in[2];
  const float* c0  = (const float*)d_in[3];
  const float* w1  = (const float*)d_in[4];
  const float* b1  = (const float*)d_in[5];
  const float* w2  = (const float*)d_in[6];
  const float* b2  = (const float*)d_in[7];
  const float* w3  = (const float*)d_in[8];
  const float* b3  = (const float*)d_in[9];
  const float* wf  = (const float*)d_in[10];
  const float* bf  = (const float*)d_in[11];
  const float* wih = (const float*)d_in[12];
  const float* whh = (const float*)d_in[13];
  const float* bih = (const float*)d_in[14];
  const float* bhh = (const float*)d_in[15];
  const float* wa  = (const float*)d_in[16];
  const float* ba  = (const float*)d_in[17];
  const float* wc  = (const float*)d_in[18];
  const float* bc  = (const float*)d_in[19];
  float* out = (float*)d_out;

  char* ws = (char*)d_ws;
  size_t off = 0;
  auto alloc = [&](size_t bytes)->char*{
    char* p = ws + off;
    off += (bytes + 255) & ~(size_t)255;
    return p;
  };
  f16*  y3   = (f16*)alloc(4096UL*3136*2);     // 25.7 MB (only trunk intermediate in HBM)
  f16*  feat = (f16*)alloc(4096UL*512*2);
  float* gx  = (float*)alloc(4096UL*512*4);
  f16*  hs   = (f16*)alloc(4096UL*128*2);
  f16*  Bp1  = (f16*)alloc(32UL*32*8*2);
  f16*  Bp2  = (f16*)alloc(64UL*64*8*2);
  f16*  Bp3  = (f16*)alloc(72UL*64*8*2);
  f16*  Bpf  = (f16*)alloc(392UL*512*8*2);
  f16*  Bpih = (f16*)alloc(64UL*512*8*2);
  f16*  Bph  = (f16*)alloc(16UL*32*8*2);
  float* bsum = (float*)alloc(512UL*4);
  f16*  whhT2 = (f16*)alloc(64UL*512*2*2);     // 128 KB, L2-resident per XCD

  prep_w1<<<32, 256, 0, stream>>>(w1, Bp1);
  prep_w2<<<128, 256, 0, stream>>>(w2, Bp2);
  prep_w3<<<144, 256, 0, stream>>>(w3, Bp3);
  prep_wf<<<6272, 256, 0, stream>>>(wf, Bpf);
  prep_wih<<<1024, 256, 0, stream>>>(wih, Bpih);
  prep_wheads<<<16, 256, 0, stream>>>(wa, wc, Bph);
  prep_bsum<<<2, 256, 0, stream>>>(bih, bhh, bsum);
  prep_whh<<<256, 256, 0, stream>>>(whh, whhT2);

  conv123_k<<<4096, 256, 0, stream>>>(x, Bp1, b1, Bp2, b2, Bp3, b3, y3);
  gemm_k<true,  true ><<<dim3(64, 8), 256, 0, stream>>>(y3,   Bpf,  bf,   (void*)feat, 4096, 512, 3136);
  gemm_k<false, false><<<dim3(64, 8), 256, 0, stream>>>(feat, Bpih, bsum, (void*)gx,   4096, 512, 512);
  lstm_seg<<<dim3(128, 32), 128, 0, stream>>>(gx, whhT2, dn, h0, c0, hs);
  heads_k<<<64, 256, 0, stream>>>(hs, Bph, ba, bc, out);
}

// Round 3
// 843.959 us; speedup vs baseline: 1.3086x; 1.0636x over previous
//
#include <hip/hip_runtime.h>

typedef _Float16 f16;
typedef _Float16 f16x2 __attribute__((ext_vector_type(2)));
typedef _Float16 f16x4 __attribute__((ext_vector_type(4)));
typedef _Float16 f16x8 __attribute__((ext_vector_type(8)));
typedef float f32x4 __attribute__((ext_vector_type(4)));

__device__ __forceinline__ float sigf(float x){ return 1.f/(1.f + __expf(-x)); }
__device__ __forceinline__ float tanhfast(float x){ return 2.f/(1.f + __expf(-2.f*x)) - 1.f; }
__device__ __forceinline__ float fdot2f(f16x2 a, f16x2 b, float c){
#if __has_builtin(__builtin_amdgcn_fdot2)
  return __builtin_amdgcn_fdot2(a, b, c, false);
#else
  return c + (float)a.x*(float)b.x + (float)a.y*(float)b.y;
#endif
}

// ---------------- weight prep kernels (Bpack layout: [k>>3][n][k&7]) ----------------
__global__ void prep_w1(const float* __restrict__ w, f16* __restrict__ dst){
  int idx = blockIdx.x*256 + threadIdx.x;            // 32*4*8*8 = 8192
  if (idx >= 8192) return;
  int och = idx >> 8, rem = idx & 255;
  int c = rem >> 6, ky = (rem >> 3) & 7, kx = rem & 7;
  int k = c*64 + ky*8 + kx;                           // K-order (c,ky,kx), K=256
  dst[(k>>3)*256 + och*8 + (k&7)] = (f16)(w[idx] * (1.f/255.f));  // fold x/255
}
__global__ void prep_w2(const float* __restrict__ w, f16* __restrict__ dst){
  int idx = blockIdx.x*256 + threadIdx.x;            // 64*32*4*4 = 32768
  if (idx >= 32768) return;
  int och = idx >> 9;
  int c = (idx >> 4) & 31, ky = (idx >> 2) & 3, kx = idx & 3;
  int k = (ky*4 + kx)*32 + c;                         // K=512
  dst[(k>>3)*512 + och*8 + (k&7)] = (f16)w[idx];
}
__global__ void prep_w3(const float* __restrict__ w, f16* __restrict__ dst){
  int idx = blockIdx.x*256 + threadIdx.x;            // 64*64*3*3 = 36864
  if (idx >= 36864) return;
  int och = idx / 576, r = idx % 576;
  int c = r / 9, r2 = r % 9;
  int ky = r2 / 3, kx = r2 % 3;
  int k = (ky*3 + kx)*64 + c;                         // K=576
  dst[(k>>3)*512 + och*8 + (k&7)] = (f16)w[idx];
}
__global__ void prep_wf(const float* __restrict__ w, f16* __restrict__ dst){
  int idx = blockIdx.x*256 + threadIdx.x;            // 392*512*8 = 1605632
  if (idx >= 392*512*8) return;
  int j = idx & 7, n = (idx >> 3) & 511, k8 = idx >> 12;
  int kf = k8*8 + j;
  int c = kf & 63, p = kf >> 6;                      // p = iy*7+ix (0..48)
  dst[idx] = (f16)w[(size_t)n*3136 + c*49 + p];
}
__global__ void prep_wih(const float* __restrict__ w, f16* __restrict__ dst){
  int idx = blockIdx.x*256 + threadIdx.x;            // 64*512*8 = 262144
  if (idx >= 262144) return;
  int j = idx & 7, n = (idx >> 3) & 511, k8 = idx >> 12;
  dst[idx] = (f16)w[n*512 + k8*8 + j];               // fully coalesced r+w
}
__global__ void prep_wheads(const float* __restrict__ wa, const float* __restrict__ wc,
                            f16* __restrict__ dst){
  int idx = blockIdx.x*256 + threadIdx.x;            // 32*128 (pad N 19->32)
  if (idx >= 4096) return;
  int n = idx >> 7, k = idx & 127;
  float v = 0.f;
  if (n < 18) v = wa[n*128 + k];
  else if (n == 18) v = wc[k];
  dst[(k>>3)*256 + n*8 + (k&7)] = (f16)v;
}
__global__ void prep_bsum(const float* __restrict__ a, const float* __restrict__ b,
                          float* __restrict__ s){
  int i = blockIdx.x*256 + threadIdx.x;
  if (i < 512) s[i] = a[i] + b[i];
}
// whhT2 layout: [k2=k/2][n=0..511][k&1] fp16 -> coalesced f16x2 loads per (k2, gate)
__global__ void prep_whh(const float* __restrict__ w, f16* __restrict__ dst){
  int idx = blockIdx.x*256 + threadIdx.x;            // 512*128 = 65536
  if (idx >= 65536) return;
  int nn = idx >> 7, k = idx & 127;
  dst[(k >> 1)*1024 + nn*2 + (k & 1)] = (f16)w[idx];
}

// ---------------- fused conv trunk: x frame -> y3 (49*64 fp16), all LDS-resident ----------------
// one block per frame. conv1 in FOUR 24-row slabs with register-batched staging (8 float4
// in flight) and cross-slab prefetch; MFMA operands SWAPPED (A/B frags are layout-symmetric
// for 16x16x32) so each lane's 4 acc values are och-contiguous -> f16x4 vector epilogues.
__global__ __launch_bounds__(256, 3) void conv123_k(const float* __restrict__ x,
    const f16* __restrict__ Bp1, const float* __restrict__ b1,
    const f16* __restrict__ Bp2, const float* __restrict__ b2,
    const f16* __restrict__ Bp3, const float* __restrict__ b3,
    f16* __restrict__ y3){
  __shared__ alignas(16) f16 xt[4*24*84];            // 16128 B; reused as y2 (81*64 swz)
  __shared__ alignas(16) f16 y1t[400*32];            // 25600 B  (total 41728 B -> 3 blk/CU)
  int n = blockIdx.x;
  int tid = threadIdx.x;
  int lane = tid & 63, w = tid >> 6;
  int q = lane >> 4, m = lane & 15;
  int wg = w & 1, wm = w >> 1;
  const float* xn = x + (size_t)n*4*84*84;

  // prologue: issue slab-0 loads (8 in flight per thread)
  float4 fl[8];
  #pragma unroll
  for (int u = 0; u < 8; ++u){
    int i = tid + u*256; if (i > 2015) i = 2015;
    int c = i / 504, r = i % 504;
    int iy = r / 21, x4 = r % 21;
    fl[u] = *((const float4*)(xn + (c*84 + iy)*84) + x4);
  }
  int och1 = wg*16 + m;
  f16x8 bfr1[8];
  #pragma unroll
  for (int s = 0; s < 8; ++s)
    bfr1[s] = *(const f16x8*)(Bp1 + ((4*s + q)*32 + och1)*8);
  f32x4 bias1v = *(const f32x4*)(b1 + wg*16 + q*4);

  #pragma unroll
  for (int h = 0; h < 4; ++h){
    __syncthreads();                                 // prev slab's compute done -> xt free
    // drain fl -> xt (fp16 planar [c][24][84])
    #pragma unroll
    for (int u = 0; u < 8; ++u){
      int i = tid + u*256; if (i > 2015) i = 2015;
      int c = i / 504, r = i % 504;
      int iy = r / 21, x4 = r % 21;
      float4 v = fl[u];
      f16x4 hv = { (f16)v.x, (f16)v.y, (f16)v.z, (f16)v.w };
      *(f16x4*)(&xt[(c*24 + iy)*84 + x4*4]) = hv;
    }
    // issue next slab's loads: latency hides under this slab's MFMA phase
    if (h < 3){
      #pragma unroll
      for (int u = 0; u < 8; ++u){
        int i = tid + u*256; if (i > 2015) i = 2015;
        int c = i / 504, r = i % 504;
        int iy = r / 21, x4 = r % 21;
        fl[u] = *((const float4*)(xn + (c*84 + (h+1)*20 + iy)*84) + x4);
      }
    }
    __syncthreads();
    // conv1 slab h: swapped mfma -> lane holds och = wg*16+q*4+r, px = i2*16+m
    int oy4[4], ox4[4];
    #pragma unroll
    for (int i2 = 0; i2 < 4; ++i2){
      int pl = i2*16 + m; if (pl > 49) pl = 49;
      int p = wm*50 + pl;
      oy4[i2] = (p/20)*4; ox4[i2] = (p%20)*4;
    }
    f32x4 acc1[4] = {};
    #pragma unroll
    for (int s = 0; s < 8; ++s){
      int k8 = 4*s + q;
      int c = k8 >> 3, ky = k8 & 7;                  // K-order (c,ky,kx)
      #pragma unroll
      for (int i2 = 0; i2 < 4; ++i2){
        const f16* ap = &xt[(c*24 + oy4[i2] + ky)*84 + ox4[i2]];
        f16x4 lo = *(const f16x4*)ap;
        f16x4 hi = *(const f16x4*)(ap + 4);
        f16x8 a = __builtin_shufflevector(lo, hi, 0,1,2,3,4,5,6,7);
        acc1[i2] = __builtin_amdgcn_mfma_f32_16x16x32_f16(bfr1[s], a, acc1[i2], 0, 0, 0);
      }
    }
    #pragma unroll
    for (int i2 = 0; i2 < 4; ++i2){
      int pl = i2*16 + m;
      if (pl < 50){
        int P = h*100 + wm*50 + pl;                  // global y1 pixel 0..399
        f16x4 hv;
        #pragma unroll
        for (int r = 0; r < 4; ++r){
          float v = acc1[i2][r] + bias1v[r]; v = v > 0.f ? v : 0.f;
          hv[r] = (f16)v;
        }
        int idx = (P*32 + wg*16 + q*4) ^ (((P>>1)&7)<<3);   // swizzled f16x4 write
        *(f16x4*)(&y1t[idx]) = hv;
      }
    }
  }
  __syncthreads();                                   // y1t complete

  // ---- conv2: y1t (20x20x32 swz) -> y2 (9x9x64 swz) in xt; swapped mfma ----
  int och2 = w*16 + m;
  f16x8 bfr2[16];
  #pragma unroll
  for (int s = 0; s < 16; ++s)
    bfr2[s] = *(const f16x8*)(Bp2 + ((size_t)(4*s + q)*64 + och2)*8);
  int basev[6];
  #pragma unroll
  for (int i = 0; i < 6; ++i){
    int px = i*16 + m; if (px > 80) px = 80;
    basev[i] = (px/9*2)*20 + (px%9)*2;
  }
  f32x4 acc2[6] = {};
  #pragma unroll
  for (int s = 0; s < 16; ++s){
    int k8 = 4*s + q;
    int c0 = (k8 & 3)*8;
    int kk = k8 >> 2;
    int poff = (kk >> 2)*20 + (kk & 3);              // ky*20+kx
    #pragma unroll
    for (int i = 0; i < 6; ++i){
      int p = basev[i] + poff;
      int idx = (p*32 + c0) ^ (((p>>1)&7)<<3);       // swizzled read
      f16x8 a = *(const f16x8*)(&y1t[idx]);
      acc2[i] = __builtin_amdgcn_mfma_f32_16x16x32_f16(bfr2[s], a, acc2[i], 0, 0, 0);
    }
  }
  f32x4 bias2v = *(const f32x4*)(b2 + w*16 + q*4);
  #pragma unroll
  for (int i = 0; i < 6; ++i){
    int px = i*16 + m;
    if (px < 81){
      f16x4 hv;
      #pragma unroll
      for (int r = 0; r < 4; ++r){
        float v = acc2[i][r] + bias2v[r]; v = v > 0.f ? v : 0.f;
        hv[r] = (f16)v;
      }
      int idx = (px*64 + w*16 + q*4) ^ ((px&7)<<3);  // y2 in xt, swizzled f16x4
      *(f16x4*)(&xt[idx]) = hv;
    }
  }
  __syncthreads();

  // ---- conv3: y2 (9x9x64 swz) -> y3 global (49x64); swapped mfma ----
  int basev3[4];
  #pragma unroll
  for (int i = 0; i < 4; ++i){
    int px = i*16 + m; if (px > 48) px = 48;
    basev3[i] = (px/7)*9 + (px%7);
  }
  f32x4 acc3[4] = {};
  for (int s = 0; s < 18; ++s){
    int k8 = 4*s + q;
    int c0 = (k8 & 7)*8;
    int kxy = k8 >> 3;
    int ky = kxy/3, kx = kxy%3;
    f16x8 b = *(const f16x8*)(Bp3 + ((size_t)k8*64 + och2)*8);
    int poff = ky*9 + kx;
    #pragma unroll
    for (int i = 0; i < 4; ++i){
      int p = basev3[i] + poff;
      int idx = (p*64 + c0) ^ ((p&7)<<3);            // swizzled read
      f16x8 a = *(const f16x8*)(&xt[idx]);
      acc3[i] = __builtin_amdgcn_mfma_f32_16x16x32_f16(b, a, acc3[i], 0, 0, 0);
    }
  }
  f32x4 bias3v = *(const f32x4*)(b3 + w*16 + q*4);
  #pragma unroll
  for (int i = 0; i < 4; ++i){
    int px = i*16 + m;
    if (px < 49){
      f16x4 hv;
      #pragma unroll
      for (int r = 0; r < 4; ++r){
        float v = acc3[i][r] + bias3v[r]; v = v > 0.f ? v : 0.f;
        hv[r] = (f16)v;
      }
      *(f16x4*)(&y3[((size_t)n*49 + px)*64 + w*16 + q*4]) = hv;  // 8B coalesced store
    }
  }
}

// ---------------- generic GEMM: out(M,N) = A(M,K)fp16 @ Bpack + bias ----------------
template<bool RELU, bool OUTH>
__global__ __launch_bounds__(256) void gemm_k(const f16* __restrict__ A,
    const f16* __restrict__ Bp, const float* __restrict__ bias, void* __restrict__ out,
    int M, int N, int K){
  __shared__ alignas(16) f16 at[64*264];             // 64 rows, K_BLK=256 (+8 pad)
  int m0 = blockIdx.x*64, n0 = blockIdx.y*64;
  int lane = threadIdx.x & 63, w = threadIdx.x >> 6;
  int q = lane >> 4, cl = lane & 15;
  int mh = w >> 1, nh = w & 1;
  f32x4 acc[2][2] = {};
  for (int kb = 0; kb < K; kb += 256){
    int kblen = K - kb; if (kblen > 256) kblen = 256;
    int c8n = kblen >> 3;
    __syncthreads();
    int tot = 64*c8n;
    for (int i = threadIdx.x; i < tot; i += 256){
      int row, c8;
      if (c8n == 32){ row = i >> 5; c8 = i & 31; } else { row = i >> 3; c8 = i & 7; }
      *(f16x8*)(&at[row*264 + c8*8]) = *(const f16x8*)(&A[(size_t)(m0+row)*K + kb + c8*8]);
    }
    __syncthreads();
    int nks = kblen >> 5;
    for (int s = 0; s < nks; ++s){
      f16x8 a[2], b[2];
      #pragma unroll
      for (int mi = 0; mi < 2; ++mi)
        a[mi] = *(const f16x8*)(&at[((mh*2+mi)*16 + cl)*264 + 32*s + 8*q]);
      #pragma unroll
      for (int ni = 0; ni < 2; ++ni){
        int nn = n0 + (nh*2+ni)*16 + cl;
        b[ni] = *(const f16x8*)(&Bp[((size_t)((kb>>3) + 4*s + q)*N + nn)*8]);
      }
      #pragma unroll
      for (int mi = 0; mi < 2; ++mi)
        #pragma unroll
        for (int ni = 0; ni < 2; ++ni)
          acc[mi][ni] = __builtin_amdgcn_mfma_f32_16x16x32_f16(a[mi], b[ni], acc[mi][ni], 0,0,0);
    }
  }
  #pragma unroll
  for (int ni = 0; ni < 2; ++ni){
    int nn = n0 + (nh*2+ni)*16 + cl;
    float bv = bias[nn];
    #pragma unroll
    for (int mi = 0; mi < 2; ++mi)
      #pragma unroll
      for (int r = 0; r < 4; ++r){
        int mg = m0 + (mh*2+mi)*16 + q*4 + r;
        float v = acc[mi][ni][r] + bv;
        if (RELU) v = v > 0.f ? v : 0.f;
        if (OUTH) ((f16*)out)[(size_t)mg*N + nn] = (f16)v;
        else      ((float*)out)[(size_t)mg*N + nn] = v;
      }
  }
}

// ---------------- segmented LSTM: done==1 resets state -> independent segments ----------------
__global__ __launch_bounds__(128) void lstm_seg(const float* __restrict__ gx,
    const f16* __restrict__ whhT2, const int* __restrict__ done,
    const float* __restrict__ h0, const float* __restrict__ c0,
    f16* __restrict__ hs){
  int e = blockIdx.y, t0 = blockIdx.x;
  if (t0 > 0 && done[t0*32 + e] == 0) return;        // uniform early exit
  int j = threadIdx.x;
  __shared__ f16 hl[2][128];
  float h, c;
  if (t0 == 0){
    float mm = 1.f - (float)done[e];                 // done[t=0, e]
    h = h0[e*128 + j]*mm;
    c = c0[e*128 + j]*mm;
  } else { h = 0.f; c = 0.f; }                       // reset state at segment start
  int buf = 0;
  hl[0][j] = (f16)h;
  __syncthreads();
  const f16x2* wp = (const f16x2*)whhT2;
  for (int t = t0; t < 128; ++t){
    if (t > t0 && done[t*32 + e] != 0) break;        // uniform across block
    const float* gxr = gx + ((size_t)t*32 + e)*512;
    float gi = gxr[j], gf = gxr[128 + j], gg = gxr[256 + j], go = gxr[384 + j];
    const f16x2* hp = (const f16x2*)hl[buf];
    float ai = 0.f, af = 0.f, ag = 0.f, ao = 0.f;
    #pragma unroll 8
    for (int k2 = 0; k2 < 64; ++k2){
      f16x2 hv = hp[k2];                             // LDS broadcast, conflict-free
      const f16x2* wr = wp + k2*512;
      ai = fdot2f(wr[j], hv, ai);
      af = fdot2f(wr[128 + j], hv, af);
      ag = fdot2f(wr[256 + j], hv, ag);
      ao = fdot2f(wr[384 + j], hv, ao);
    }
    gi += ai; gf += af; gg += ag; go += ao;
    c = sigf(gf)*c + sigf(gi)*tanhfast(gg);
    h = sigf(go)*tanhfast(c);
    hs[((size_t)t*32 + e)*128 + j] = (f16)h;
    buf ^= 1;
    hl[buf][j] = (f16)h;                             // double buffer: 1 barrier/step
    __syncthreads();
  }
}

// ---------------- heads: (TB,128) @ [wa;wc]^T + bias -> out (TB,19) fp32 ----------------
__global__ __launch_bounds__(256) void heads_k(const f16* __restrict__ hs,
    const f16* __restrict__ Bp, const float* __restrict__ ba, const float* __restrict__ bc,
    float* __restrict__ out){
  __shared__ alignas(16) f16 at[64*128];
  int m0 = blockIdx.x*64;
  for (int i = threadIdx.x; i < 1024; i += 256)
    ((uint4*)at)[i] = ((const uint4*)(hs + (size_t)m0*128))[i];
  int lane = threadIdx.x & 63, w = threadIdx.x >> 6;
  int q = lane >> 4, cl = lane & 15;
  __syncthreads();
  f32x4 acc[2] = {};
  #pragma unroll
  for (int s = 0; s < 4; ++s){
    f16x8 a = *(const f16x8*)(&at[(w*16 + cl)*128 + 32*s + 8*q]);
    #pragma unroll
    for (int nt = 0; nt < 2; ++nt){
      f16x8 b = *(const f16x8*)(&Bp[((4*s + q)*32 + nt*16 + cl)*8]);
      acc[nt] = __builtin_amdgcn_mfma_f32_16x16x32_f16(a, b, acc[nt], 0,0,0);
    }
  }
  #pragma unroll
  for (int nt = 0; nt < 2; ++nt){
    int n = nt*16 + cl;
    if (n < 19){
      float bv = (n < 18) ? ba[n] : bc[0];
      #pragma unroll
      for (int r = 0; r < 4; ++r){
        int m = m0 + w*16 + q*4 + r;
        out[(size_t)m*19 + n] = acc[nt][r] + bv;
      }
    }
  }
}

extern "C" void kernel_launch(void* const* d_in, const int* in_sizes, int n_in,
                              void* d_out, int out_size, void* d_ws, size_t ws_size,
                              hipStream_t stream){
  const float* x   = (const float*)d_in[0];
  const int*   dn  = (const int*)d_in[1];
  const float* h0  = (const float*)d_in[2];
  const float* c0  = (const float*)d_in[3];
  const float* w1  = (const float*)d_in[4];
  const float* b1  = (const float*)d_in[5];
  const float* w2  = (const float*)d_in[6];
  const float* b2  = (const float*)d_in[7];
  const float* w3  = (const float*)d_in[8];
  const float* b3  = (const float*)d_in[9];
  const float* wf  = (const float*)d_in[10];
  const float* bf  = (const float*)d_in[11];
  const float* wih = (const float*)d_in[12];
  const float* whh = (const float*)d_in[13];
  const float* bih = (const float*)d_in[14];
  const float* bhh = (const float*)d_in[15];
  const float* wa  = (const float*)d_in[16];
  const float* ba  = (const float*)d_in[17];
  const float* wc  = (const float*)d_in[18];
  const float* bc  = (const float*)d_in[19];
  float* out = (float*)d_out;

  char* ws = (char*)d_ws;
  size_t off = 0;
  auto alloc = [&](size_t bytes)->char*{
    char* p = ws + off;
    off += (bytes + 255) & ~(size_t)255;
    return p;
  };
  f16*  y3   = (f16*)alloc(4096UL*3136*2);     // 25.7 MB (only trunk intermediate in HBM)
  f16*  feat = (f16*)alloc(4096UL*512*2);
  float* gx  = (float*)alloc(4096UL*512*4);
  f16*  hs   = (f16*)alloc(4096UL*128*2);
  f16*  Bp1  = (f16*)alloc(32UL*32*8*2);
  f16*  Bp2  = (f16*)alloc(64UL*64*8*2);
  f16*  Bp3  = (f16*)alloc(72UL*64*8*2);
  f16*  Bpf  = (f16*)alloc(392UL*512*8*2);
  f16*  Bpih = (f16*)alloc(64UL*512*8*2);
  f16*  Bph  = (f16*)alloc(16UL*32*8*2);
  float* bsum = (float*)alloc(512UL*4);
  f16*  whhT2 = (f16*)alloc(64UL*512*2*2);     // 128 KB, L2-resident per XCD

  prep_w1<<<32, 256, 0, stream>>>(w1, Bp1);
  prep_w2<<<128, 256, 0, stream>>>(w2, Bp2);
  prep_w3<<<144, 256, 0, stream>>>(w3, Bp3);
  prep_wf<<<6272, 256, 0, stream>>>(wf, Bpf);
  prep_wih<<<1024, 256, 0, stream>>>(wih, Bpih);
  prep_wheads<<<16, 256, 0, stream>>>(wa, wc, Bph);
  prep_bsum<<<2, 256, 0, stream>>>(bih, bhh, bsum);
  prep_whh<<<256, 256, 0, stream>>>(whh, whhT2);

  conv123_k<<<4096, 256, 0, stream>>>(x, Bp1, b1, Bp2, b2, Bp3, b3, y3);
  gemm_k<true,  true ><<<dim3(64, 8), 256, 0, stream>>>(y3,   Bpf,  bf,   (void*)feat, 4096, 512, 3136);
  gemm_k<false, false><<<dim3(64, 8), 256, 0, stream>>>(feat, Bpih, bsum, (void*)gx,   4096, 512, 512);
  lstm_seg<<<dim3(128, 32), 128, 0, stream>>>(gx, whhT2, dn, h0, c0, hs);
  heads_k<<<64, 256, 0, stream>>>(hs, Bph, ba, bc, out);
}